// Round 1
// baseline (737.367 us; speedup 1.0000x reference)
//
#include <hip/hip_runtime.h>
#include <math.h>

#define BSZ   8192
#define DDIM  256
#define SCALE 33.33333333333333f   // 1/0.03
#define C_OFF 34.0f

#define TM 64
#define TN 64
#define BK 16
#define COL_GROUPS 4
#define COLS_PER_GROUP (BSZ / COL_GROUPS)   // 2048
#define TILES_PER_GROUP (COLS_PER_GROUP / TN) // 32

// Kernel 1: tiled fp32 GEMM (z_a @ z_t^T), fused mask+exp+row/col sum epilogue.
// s_row[i] = sum_j mask * exp(sim_ij - C);  s_col[j] = sum_i mask * exp(sim_ij - C)
__global__ __launch_bounds__(256) void sim_lse_kernel(
    const float* __restrict__ za, const float* __restrict__ zt,
    const int* __restrict__ pid,
    float* __restrict__ s_row, float* __restrict__ s_col)
{
    __shared__ __align__(16) float As[BK][TM];   // A^T chunk: As[k][m]
    __shared__ __align__(16) float Bs[BK][TN];   // B^T chunk: Bs[k][n]
    __shared__ float colsum[COLS_PER_GROUP];     // 8 KB, whole col-group
    __shared__ float rowsum[TM];

    const int tid      = threadIdx.x;
    const int row0     = blockIdx.x * TM;
    const int col_base = blockIdx.y * COLS_PER_GROUP;

    for (int i = tid; i < COLS_PER_GROUP; i += 256) colsum[i] = 0.f;
    if (tid < TM) rowsum[tid] = 0.f;

    const int tx    = tid & 15;          // micro-tile col group 0..15
    const int ty    = tid >> 4;          // micro-tile row group 0..15
    const int rbase = ty * 4;
    const int cbase = tx * 4;

    // staging mapping: one float4 per thread per tensor per K-chunk
    const int sm = tid >> 2;             // row/col within tile, 0..63
    const int sk = (tid & 3) * 4;        // k offset within chunk (float4)

    int pid_r[4];
    #pragma unroll
    for (int i = 0; i < 4; i++) pid_r[i] = pid[row0 + rbase + i];

    float row_acc[4] = {0.f, 0.f, 0.f, 0.f};

    __syncthreads();

    for (int t = 0; t < TILES_PER_GROUP; t++) {
        const int col0 = col_base + t * TN;
        float acc[4][4] = {};

        for (int kt = 0; kt < DDIM; kt += BK) {
            const float4 a4 = *(const float4*)&za[(row0 + sm) * DDIM + kt + sk];
            const float4 b4 = *(const float4*)&zt[(col0 + sm) * DDIM + kt + sk];
            As[sk + 0][sm] = a4.x; As[sk + 1][sm] = a4.y;
            As[sk + 2][sm] = a4.z; As[sk + 3][sm] = a4.w;
            Bs[sk + 0][sm] = b4.x; Bs[sk + 1][sm] = b4.y;
            Bs[sk + 2][sm] = b4.z; Bs[sk + 3][sm] = b4.w;
            __syncthreads();

            #pragma unroll
            for (int kk = 0; kk < BK; kk++) {
                const float4 a = *(const float4*)&As[kk][rbase];
                const float4 b = *(const float4*)&Bs[kk][cbase];
                const float av[4] = {a.x, a.y, a.z, a.w};
                const float bv[4] = {b.x, b.y, b.z, b.w};
                #pragma unroll
                for (int i = 0; i < 4; i++)
                    #pragma unroll
                    for (int j = 0; j < 4; j++)
                        acc[i][j] = fmaf(av[i], bv[j], acc[i][j]);
            }
            __syncthreads();
        }

        // epilogue: mask + exp + accumulate
        int pid_c[4];
        #pragma unroll
        for (int j = 0; j < 4; j++) pid_c[j] = pid[col0 + cbase + j];

        float col_acc[4] = {0.f, 0.f, 0.f, 0.f};
        #pragma unroll
        for (int i = 0; i < 4; i++) {
            const int gr = row0 + rbase + i;
            #pragma unroll
            for (int j = 0; j < 4; j++) {
                const int gc = col0 + cbase + j;
                const bool keep = (pid_r[i] != pid_c[j]) || (gr == gc);
                const float e = keep ? __expf(fmaf(acc[i][j], SCALE, -C_OFF)) : 0.f;
                row_acc[i] += e;
                col_acc[j] += e;
            }
        }
        #pragma unroll
        for (int j = 0; j < 4; j++)
            atomicAdd(&colsum[t * TN + cbase + j], col_acc[j]);
    }

    #pragma unroll
    for (int i = 0; i < 4; i++)
        atomicAdd(&rowsum[rbase + i], row_acc[i]);
    __syncthreads();

    if (tid < TM) atomicAdd(&s_row[row0 + tid], rowsum[tid]);
    for (int i = tid; i < COLS_PER_GROUP; i += 256)
        atomicAdd(&s_col[col_base + i], colsum[i]);
}

// Kernel 2: per-row loss contributions -> one scalar accumulator; validity flag.
__global__ __launch_bounds__(256) void finalize_rows(
    const float* __restrict__ za, const float* __restrict__ zt,
    const int* __restrict__ pid,
    const float* __restrict__ s_row, const float* __restrict__ s_col,
    float* __restrict__ total, int* __restrict__ flag)
{
    const int i = blockIdx.x * 256 + threadIdx.x;   // row index, grid covers 8192

    // pos_i = dot(z_a[i], z_t[i]) * SCALE
    const float4* a4 = (const float4*)&za[i * DDIM];
    const float4* t4 = (const float4*)&zt[i * DDIM];
    float pos = 0.f;
    #pragma unroll 4
    for (int k = 0; k < DDIM / 4; k++) {
        const float4 a = a4[k], t = t4[k];
        pos = fmaf(a.x, t.x, pos); pos = fmaf(a.y, t.y, pos);
        pos = fmaf(a.z, t.z, pos); pos = fmaf(a.w, t.w, pos);
    }
    pos *= SCALE;

    const float c = (logf(s_row[i]) + C_OFF - pos)
                  + (logf(s_col[i]) + C_OFF - pos);

    // wave reduce (width 64) + one atomic per wave
    float v = c;
    #pragma unroll
    for (int off = 32; off > 0; off >>= 1) v += __shfl_down(v, off, 64);
    if ((threadIdx.x & 63) == 0) atomicAdd(total, v);

    // validity: any pid differs from pid[0] ?
    const unsigned long long m = __ballot(pid[i] != pid[0]);
    if (m != 0ull && (threadIdx.x & 63) == 0) atomicOr(flag, 1);
}

__global__ void write_out(const float* __restrict__ total,
                          const int* __restrict__ flag,
                          float* __restrict__ out)
{
    out[0] = (*flag) ? (*total) / (2.0f * (float)BSZ) : 0.0f;
}

extern "C" void kernel_launch(void* const* d_in, const int* in_sizes, int n_in,
                              void* d_out, int out_size, void* d_ws, size_t ws_size,
                              hipStream_t stream)
{
    const float* za  = (const float*)d_in[0];
    const float* zt  = (const float*)d_in[1];
    const int*   pid = (const int*)d_in[2];
    float* out = (float*)d_out;

    float* s_row = (float*)d_ws;
    float* s_col = s_row + BSZ;
    float* total = s_col + BSZ;
    int*   flag  = (int*)(total + 1);

    hipMemsetAsync(d_ws, 0, (size_t)(2 * BSZ + 2) * sizeof(float), stream);

    sim_lse_kernel<<<dim3(BSZ / TM, COL_GROUPS), 256, 0, stream>>>(
        za, zt, pid, s_row, s_col);
    finalize_rows<<<dim3(BSZ / 256), 256, 0, stream>>>(
        za, zt, pid, s_row, s_col, total, flag);
    write_out<<<1, 1, 0, stream>>>(total, flag, out);
}

// Round 2
// 162.571 us; speedup vs baseline: 4.5357x; 4.5357x over previous
//
#include <hip/hip_runtime.h>
#include <math.h>

#define BSZ   8192
#define DDIM  256
#define SCALE 33.33333333333333f   // 1/0.03
#define C_OFF 34.0f                // fixed LSE offset: |sim*SCALE| <= 33.34

typedef __bf16 bf16_t;
typedef __bf16 bf16x8 __attribute__((ext_vector_type(8)));
typedef float  floatx4 __attribute__((ext_vector_type(4)));

// ---------------------------------------------------------------- cvt fp32->bf16
__global__ __launch_bounds__(256) void cvt_kernel(const float* __restrict__ a,
                                                  const float* __restrict__ b,
                                                  bf16_t* __restrict__ oa,
                                                  bf16_t* __restrict__ ob)
{
    const float* in = blockIdx.y ? b : a;
    bf16_t* out     = blockIdx.y ? ob : oa;
    const int i = (blockIdx.x * 256 + threadIdx.x) * 8;
    const float4 x = *(const float4*)&in[i];
    const float4 y = *(const float4*)&in[i + 4];
    bf16x8 v;
    v[0] = (bf16_t)x.x; v[1] = (bf16_t)x.y; v[2] = (bf16_t)x.z; v[3] = (bf16_t)x.w;
    v[4] = (bf16_t)y.x; v[5] = (bf16_t)y.y; v[6] = (bf16_t)y.z; v[7] = (bf16_t)y.w;
    *(bf16x8*)&out[i] = v;
}

// async global -> LDS, 16 bytes per lane (wave-uniform LDS base + lane*16)
__device__ __forceinline__ void gl_lds16(const bf16_t* g, void* l)
{
    __builtin_amdgcn_global_load_lds(
        (const __attribute__((address_space(1))) void*)g,
        (__attribute__((address_space(3))) void*)l, 16, 0, 0);
}

// ---------------------------------------------------------------- main MFMA kernel
// One block computes a 128x128 tile of sim = za @ zt^T (bf16 MFMA),
// then fused epilogue: mask + exp(sim*SCALE - C) + row/col partial sums.
__global__ __launch_bounds__(256) void sim_mfma_kernel(
    const bf16_t* __restrict__ za, const bf16_t* __restrict__ zt,
    const int* __restrict__ pid,
    float* __restrict__ s_row, float* __restrict__ s_col)
{
    __shared__ __align__(16) bf16_t As[128 * 32];   // [row][k], 64 B/row
    __shared__ __align__(16) bf16_t Bs[128 * 32];   // [col][k]
    __shared__ int pidr[128];
    __shared__ int pidc[128];

    // tile swizzle for L2 locality (groups of 8 row-tiles)
    const int nbn = 64, GM = 8;
    const int bid   = blockIdx.x;
    const int group = bid / (GM * nbn);
    const int first = group * GM;
    const int gsz   = min(GM, 64 - first);
    const int tile_m = first + (bid % (GM * nbn)) % gsz;
    const int tile_n = (bid % (GM * nbn)) / gsz;

    const int row0 = tile_m * 128, col0 = tile_n * 128;
    const int tid  = threadIdx.x;
    const int lane = tid & 63, wid = tid >> 6;
    const int wave_m = wid >> 1, wave_n = wid & 1;
    const int quad = lane >> 4, lc = lane & 15;

    if (tid < 128) pidr[tid] = pid[row0 + tid];
    else           pidc[tid - 128] = pid[col0 + tid - 128];

    // staging: per wave 2 issues for A + 2 for B; each issue fills 16 rows x 32 k
    const int srow0 = (wid * 2 + 0) * 16 + (lane >> 2);
    const int srow1 = (wid * 2 + 1) * 16 + (lane >> 2);
    const int skoff = (lane & 3) * 8;
    const bf16_t* gA0 = za + (size_t)(row0 + srow0) * DDIM + skoff;
    const bf16_t* gA1 = za + (size_t)(row0 + srow1) * DDIM + skoff;
    const bf16_t* gB0 = zt + (size_t)(col0 + srow0) * DDIM + skoff;
    const bf16_t* gB1 = zt + (size_t)(col0 + srow1) * DDIM + skoff;
    char* lA0 = (char*)As + (wid * 2 + 0) * 1024;
    char* lA1 = (char*)As + (wid * 2 + 1) * 1024;
    char* lB0 = (char*)Bs + (wid * 2 + 0) * 1024;
    char* lB1 = (char*)Bs + (wid * 2 + 1) * 1024;

    floatx4 acc[4][4];
    #pragma unroll
    for (int m = 0; m < 4; m++)
        #pragma unroll
        for (int n = 0; n < 4; n++)
            acc[m][n] = (floatx4){0.f, 0.f, 0.f, 0.f};

    // fragment LDS byte offsets (constant across K loop)
    const int abase = (wave_m * 64 + lc) * 64 + quad * 16;
    const int bbase = (wave_n * 64 + lc) * 64 + quad * 16;
    const char* AsB = (const char*)As;
    const char* BsB = (const char*)Bs;

    for (int kt = 0; kt < DDIM; kt += 32) {
        gl_lds16(gA0 + kt, lA0);
        gl_lds16(gA1 + kt, lA1);
        gl_lds16(gB0 + kt, lB0);
        gl_lds16(gB1 + kt, lB1);
        __syncthreads();   // drains vmcnt -> LDS tiles complete

        bf16x8 af[4], bfr[4];
        #pragma unroll
        for (int m = 0; m < 4; m++) af[m]  = *(const bf16x8*)(AsB + abase + m * 1024);
        #pragma unroll
        for (int n = 0; n < 4; n++) bfr[n] = *(const bf16x8*)(BsB + bbase + n * 1024);

        #pragma unroll
        for (int m = 0; m < 4; m++)
            #pragma unroll
            for (int n = 0; n < 4; n++)
                acc[m][n] = __builtin_amdgcn_mfma_f32_16x16x32_bf16(
                    af[m], bfr[n], acc[m][n], 0, 0, 0);

        __syncthreads();   // all waves done reading before next overwrite
    }

    // ---------------- epilogue: mask + exp + row/col partial sums
    // C/D layout: col = lane&15, row = quad*4 + reg  (within each 16x16 frag)
    float rowp[16];
    float colp[4] = {0.f, 0.f, 0.f, 0.f};
    #pragma unroll
    for (int i = 0; i < 16; i++) rowp[i] = 0.f;

    #pragma unroll
    for (int m = 0; m < 4; m++) {
        #pragma unroll
        for (int r = 0; r < 4; r++) {
            const int rl  = m * 16 + quad * 4 + r;   // row within tile
            const int gr  = row0 + wave_m * 64 + rl;
            const int prw = pidr[wave_m * 64 + rl];
            float rsum = 0.f;
            #pragma unroll
            for (int n = 0; n < 4; n++) {
                const int cl = n * 16 + lc;
                const int gc = col0 + wave_n * 64 + cl;
                const bool keep = (prw != pidc[wave_n * 64 + cl]) || (gr == gc);
                const float e = keep ? __expf(fmaf(acc[m][n][r], SCALE, -C_OFF)) : 0.f;
                rsum += e;
                colp[n] += e;
            }
            rowp[m * 4 + r] += rsum;
        }
    }

    // row sums: reduce across the 16 lanes sharing a quad (they cover the cols)
    #pragma unroll
    for (int i = 0; i < 16; i++) {
        #pragma unroll
        for (int b = 1; b <= 8; b <<= 1)
            rowp[i] += __shfl_xor(rowp[i], b, 64);
    }
    // every lane in the quad-group now holds all 16 row totals; lane lc writes row idx=lc
    float rw = rowp[0];
    #pragma unroll
    for (int idx = 1; idx < 16; idx++)
        rw = (lc == idx) ? rowp[idx] : rw;
    atomicAdd(&s_row[row0 + wave_m * 64 + (lc >> 2) * 16 + quad * 4 + (lc & 3)], rw);

    // col sums: reduce across quads (xor 16, 32), quad 0 writes
    #pragma unroll
    for (int n = 0; n < 4; n++) {
        colp[n] += __shfl_xor(colp[n], 16, 64);
        colp[n] += __shfl_xor(colp[n], 32, 64);
    }
    if (quad == 0) {
        #pragma unroll
        for (int n = 0; n < 4; n++)
            atomicAdd(&s_col[col0 + wave_n * 64 + n * 16 + lc], colp[n]);
    }
}

// ---------------------------------------------------------------- finalize
__global__ __launch_bounds__(256) void finalize_rows(
    const float* __restrict__ za, const float* __restrict__ zt,
    const int* __restrict__ pid,
    const float* __restrict__ s_row, const float* __restrict__ s_col,
    float* __restrict__ total, int* __restrict__ flag)
{
    const int i = blockIdx.x * 256 + threadIdx.x;

    // pos_i = dot(z_a[i], z_t[i]) * SCALE  (exact fp32)
    const float4* a4 = (const float4*)&za[i * DDIM];
    const float4* t4 = (const float4*)&zt[i * DDIM];
    float pos = 0.f;
    #pragma unroll 4
    for (int k = 0; k < DDIM / 4; k++) {
        const float4 a = a4[k], t = t4[k];
        pos = fmaf(a.x, t.x, pos); pos = fmaf(a.y, t.y, pos);
        pos = fmaf(a.z, t.z, pos); pos = fmaf(a.w, t.w, pos);
    }
    pos *= SCALE;

    const float c = (logf(s_row[i]) + C_OFF - pos)
                  + (logf(s_col[i]) + C_OFF - pos);

    float v = c;
    #pragma unroll
    for (int off = 32; off > 0; off >>= 1) v += __shfl_down(v, off, 64);
    if ((threadIdx.x & 63) == 0) atomicAdd(total, v);

    const unsigned long long m = __ballot(pid[i] != pid[0]);
    if (m != 0ull && (threadIdx.x & 63) == 0) atomicOr(flag, 1);
}

__global__ void write_out(const float* __restrict__ total,
                          const int* __restrict__ flag,
                          float* __restrict__ out)
{
    out[0] = (*flag) ? (*total) / (2.0f * (float)BSZ) : 0.0f;
}

// ---------------------------------------------------------------- launcher
extern "C" void kernel_launch(void* const* d_in, const int* in_sizes, int n_in,
                              void* d_out, int out_size, void* d_ws, size_t ws_size,
                              hipStream_t stream)
{
    const float* za  = (const float*)d_in[0];
    const float* zt  = (const float*)d_in[1];
    const int*   pid = (const int*)d_in[2];
    float* out = (float*)d_out;

    bf16_t* za_bf = (bf16_t*)d_ws;                         // 4 MB
    bf16_t* zt_bf = za_bf + (size_t)BSZ * DDIM;            // 4 MB
    float*  s_row = (float*)(zt_bf + (size_t)BSZ * DDIM);  // 32 KB
    float*  s_col = s_row + BSZ;                           // 32 KB
    float*  total = s_col + BSZ;
    int*    flag  = (int*)(total + 1);

    hipMemsetAsync(s_row, 0, (size_t)(2 * BSZ + 2) * sizeof(float), stream);

    cvt_kernel<<<dim3((BSZ * DDIM) / (256 * 8), 2), 256, 0, stream>>>(
        za, zt, za_bf, zt_bf);

    sim_mfma_kernel<<<dim3(64 * 64), 256, 0, stream>>>(
        za_bf, zt_bf, pid, s_row, s_col);

    finalize_rows<<<dim3(BSZ / 256), 256, 0, stream>>>(
        za, zt, pid, s_row, s_col, total, flag);

    write_out<<<1, 1, 0, stream>>>(total, flag, out);
}

// Round 3
// 159.205 us; speedup vs baseline: 4.6315x; 1.0211x over previous
//
#include <hip/hip_runtime.h>
#include <math.h>

#define BSZ   8192
#define DDIM  256
#define SCALE 33.33333333333333f   // 1/0.03
#define C_OFF 34.0f                // fixed LSE offset: |sim*SCALE| <= 33.34

typedef __bf16 bf16_t;
typedef __bf16 bf16x8 __attribute__((ext_vector_type(8)));
typedef float  floatx4 __attribute__((ext_vector_type(4)));

// ---------------------------------------------------------------- cvt fp32->bf16 (+ ws zeroing)
// zbase layout (floats): s_row[8192] s_col[8192] total flag cnt  -> 16387 entries
__global__ __launch_bounds__(256) void cvt_kernel(const float* __restrict__ a,
                                                  const float* __restrict__ b,
                                                  bf16_t* __restrict__ oa,
                                                  bf16_t* __restrict__ ob,
                                                  float* __restrict__ zbase)
{
    const float* in = blockIdx.y ? b : a;
    bf16_t* out     = blockIdx.y ? ob : oa;
    const int i = (blockIdx.x * 256 + threadIdx.x) * 8;
    const float4 x = *(const float4*)&in[i];
    const float4 y = *(const float4*)&in[i + 4];
    bf16x8 v;
    v[0] = (bf16_t)x.x; v[1] = (bf16_t)x.y; v[2] = (bf16_t)x.z; v[3] = (bf16_t)x.w;
    v[4] = (bf16_t)y.x; v[5] = (bf16_t)y.y; v[6] = (bf16_t)y.z; v[7] = (bf16_t)y.w;
    *(bf16x8*)&out[i] = v;

    // fused zeroing of reduction workspace (16 blocks x 256 threads x 4 floats = 16384)
    if (blockIdx.y == 0 && blockIdx.x < 16) {
        const int z = blockIdx.x * 1024 + threadIdx.x * 4;
        *(float4*)&zbase[z] = (float4){0.f, 0.f, 0.f, 0.f};
        if (blockIdx.x == 0 && threadIdx.x == 0) {
            zbase[16384] = 0.f;            // total
            ((int*)zbase)[16385] = 0;      // flag
            ((int*)zbase)[16386] = 0;      // cnt
        }
    }
}

// async global -> LDS, 16 bytes per lane (wave-uniform LDS base + lane*16)
__device__ __forceinline__ void gl_lds16(const bf16_t* g, void* l)
{
    __builtin_amdgcn_global_load_lds(
        (const __attribute__((address_space(1))) void*)g,
        (__attribute__((address_space(3))) void*)l, 16, 0, 0);
}

// ---------------------------------------------------------------- main MFMA kernel
// One block computes a 128x128 tile of sim = za @ zt^T (bf16 MFMA),
// double-buffered LDS staging (1 barrier/iter), fused epilogue:
// mask + exp(sim*SCALE - C) + row/col partial sums.
__global__ __launch_bounds__(256) void sim_mfma_kernel(
    const bf16_t* __restrict__ za, const bf16_t* __restrict__ zt,
    const int* __restrict__ pid,
    float* __restrict__ s_row, float* __restrict__ s_col)
{
    __shared__ __align__(16) bf16_t As[2][128 * 32];   // [buf][row][k], 64 B/row
    __shared__ __align__(16) bf16_t Bs[2][128 * 32];
    __shared__ int pidr[128];
    __shared__ int pidc[128];

    // tile swizzle for L2 locality (groups of 8 row-tiles)
    const int nbn = 64, GM = 8;
    const int bid   = blockIdx.x;
    const int group = bid / (GM * nbn);
    const int first = group * GM;
    const int gsz   = min(GM, 64 - first);
    const int tile_m = first + (bid % (GM * nbn)) % gsz;
    const int tile_n = (bid % (GM * nbn)) / gsz;

    const int row0 = tile_m * 128, col0 = tile_n * 128;
    const int tid  = threadIdx.x;
    const int lane = tid & 63, wid = tid >> 6;
    const int wave_m = wid >> 1, wave_n = wid & 1;
    const int quad = lane >> 4, lc = lane & 15;

    if (tid < 128) pidr[tid] = pid[row0 + tid];
    else           pidc[tid - 128] = pid[col0 + tid - 128];

    // staging: per wave 2 issues for A + 2 for B; each issue fills 16 rows x 32 k
    const int srow0 = (wid * 2 + 0) * 16 + (lane >> 2);
    const int srow1 = (wid * 2 + 1) * 16 + (lane >> 2);
    const int skoff = (lane & 3) * 8;
    const bf16_t* gA0 = za + (size_t)(row0 + srow0) * DDIM + skoff;
    const bf16_t* gA1 = za + (size_t)(row0 + srow1) * DDIM + skoff;
    const bf16_t* gB0 = zt + (size_t)(col0 + srow0) * DDIM + skoff;
    const bf16_t* gB1 = zt + (size_t)(col0 + srow1) * DDIM + skoff;
    const int sbase = wid * 2048;   // this wave's byte region within a buffer

    floatx4 acc[4][4];
    #pragma unroll
    for (int m = 0; m < 4; m++)
        #pragma unroll
        for (int n = 0; n < 4; n++)
            acc[m][n] = (floatx4){0.f, 0.f, 0.f, 0.f};

    // fragment LDS byte offsets (constant across K loop)
    const int abase = (wave_m * 64 + lc) * 64 + quad * 16;
    const int bbase = (wave_n * 64 + lc) * 64 + quad * 16;

    // prologue: stage K-chunk 0 into buffer 0
    {
        gl_lds16(gA0, (char*)As[0] + sbase);
        gl_lds16(gA1, (char*)As[0] + sbase + 1024);
        gl_lds16(gB0, (char*)Bs[0] + sbase);
        gl_lds16(gB1, (char*)Bs[0] + sbase + 1024);
    }

    #pragma unroll
    for (int kt8 = 0; kt8 < 8; kt8++) {
        const int b = kt8 & 1;
        __syncthreads();            // drains vmcnt -> buffer b complete (prefetched last iter)

        if (kt8 < 7) {              // prefetch next chunk into the other buffer
            const int ko = (kt8 + 1) * 32;
            gl_lds16(gA0 + ko, (char*)As[b ^ 1] + sbase);
            gl_lds16(gA1 + ko, (char*)As[b ^ 1] + sbase + 1024);
            gl_lds16(gB0 + ko, (char*)Bs[b ^ 1] + sbase);
            gl_lds16(gB1 + ko, (char*)Bs[b ^ 1] + sbase + 1024);
        }

        const char* AsB = (const char*)As[b];
        const char* BsB = (const char*)Bs[b];
        bf16x8 af[4], bfr[4];
        #pragma unroll
        for (int m = 0; m < 4; m++) af[m]  = *(const bf16x8*)(AsB + abase + m * 1024);
        #pragma unroll
        for (int n = 0; n < 4; n++) bfr[n] = *(const bf16x8*)(BsB + bbase + n * 1024);

        #pragma unroll
        for (int m = 0; m < 4; m++)
            #pragma unroll
            for (int n = 0; n < 4; n++)
                acc[m][n] = __builtin_amdgcn_mfma_f32_16x16x32_bf16(
                    af[m], bfr[n], acc[m][n], 0, 0, 0);
    }

    // ---------------- epilogue: mask + exp + row/col partial sums
    // C/D layout: col = lane&15, row = quad*4 + reg  (within each 16x16 frag)
    float rowp[16];
    float colp[4] = {0.f, 0.f, 0.f, 0.f};
    #pragma unroll
    for (int i = 0; i < 16; i++) rowp[i] = 0.f;

    #pragma unroll
    for (int m = 0; m < 4; m++) {
        #pragma unroll
        for (int r = 0; r < 4; r++) {
            const int rl  = m * 16 + quad * 4 + r;   // row within tile
            const int gr  = row0 + wave_m * 64 + rl;
            const int prw = pidr[wave_m * 64 + rl];
            float rsum = 0.f;
            #pragma unroll
            for (int n = 0; n < 4; n++) {
                const int cl = n * 16 + lc;
                const int gc = col0 + wave_n * 64 + cl;
                const bool keep = (prw != pidc[wave_n * 64 + cl]) || (gr == gc);
                const float e = keep ? __expf(fmaf(acc[m][n][r], SCALE, -C_OFF)) : 0.f;
                rsum += e;
                colp[n] += e;
            }
            rowp[m * 4 + r] += rsum;
        }
    }

    // row sums: reduce across the 16 lanes sharing a quad (they cover the cols)
    #pragma unroll
    for (int i = 0; i < 16; i++) {
        #pragma unroll
        for (int b2 = 1; b2 <= 8; b2 <<= 1)
            rowp[i] += __shfl_xor(rowp[i], b2, 64);
    }
    // every lane in the quad-group now holds all 16 row totals; lane lc writes row idx=lc
    float rw = rowp[0];
    #pragma unroll
    for (int idx = 1; idx < 16; idx++)
        rw = (lc == idx) ? rowp[idx] : rw;
    atomicAdd(&s_row[row0 + wave_m * 64 + (lc >> 2) * 16 + quad * 4 + (lc & 3)], rw);

    // col sums: reduce across quads (xor 16, 32), quad 0 writes
    #pragma unroll
    for (int n = 0; n < 4; n++) {
        colp[n] += __shfl_xor(colp[n], 16, 64);
        colp[n] += __shfl_xor(colp[n], 32, 64);
    }
    if (quad == 0) {
        #pragma unroll
        for (int n = 0; n < 4; n++)
            atomicAdd(&s_col[col0 + wave_n * 64 + n * 16 + lc], colp[n]);
    }
}

// ---------------------------------------------------------------- finalize (+ fused scalar write)
__global__ __launch_bounds__(256) void finalize_rows(
    const float* __restrict__ za, const float* __restrict__ zt,
    const int* __restrict__ pid,
    const float* __restrict__ s_row, const float* __restrict__ s_col,
    float* __restrict__ total, int* __restrict__ flag, int* __restrict__ cnt,
    float* __restrict__ out)
{
    const int i = blockIdx.x * 256 + threadIdx.x;

    // pos_i = dot(z_a[i], z_t[i]) * SCALE  (exact fp32)
    const float4* a4 = (const float4*)&za[i * DDIM];
    const float4* t4 = (const float4*)&zt[i * DDIM];
    float pos = 0.f;
    #pragma unroll 4
    for (int k = 0; k < DDIM / 4; k++) {
        const float4 a = a4[k], t = t4[k];
        pos = fmaf(a.x, t.x, pos); pos = fmaf(a.y, t.y, pos);
        pos = fmaf(a.z, t.z, pos); pos = fmaf(a.w, t.w, pos);
    }
    pos *= SCALE;

    const float c = (logf(s_row[i]) + C_OFF - pos)
                  + (logf(s_col[i]) + C_OFF - pos);

    float v = c;
    #pragma unroll
    for (int off = 32; off > 0; off >>= 1) v += __shfl_down(v, off, 64);
    if ((threadIdx.x & 63) == 0) atomicAdd(total, v);

    const unsigned long long m = __ballot(pid[i] != pid[0]);
    if (m != 0ull && (threadIdx.x & 63) == 0) atomicOr(flag, 1);

    // last block writes the scalar (device-scope completion counter)
    __syncthreads();        // all waves' atomics issued & drained at barrier
    __threadfence();
    if (threadIdx.x == 0) {
        const int done = atomicAdd(cnt, 1);
        if (done == (int)gridDim.x - 1) {
            const float t = atomicAdd(total, 0.0f);   // coherent read
            const int   f = atomicOr(flag, 0);        // coherent read
            out[0] = f ? t / (2.0f * (float)BSZ) : 0.0f;
        }
    }
}

// ---------------------------------------------------------------- launcher
extern "C" void kernel_launch(void* const* d_in, const int* in_sizes, int n_in,
                              void* d_out, int out_size, void* d_ws, size_t ws_size,
                              hipStream_t stream)
{
    const float* za  = (const float*)d_in[0];
    const float* zt  = (const float*)d_in[1];
    const int*   pid = (const int*)d_in[2];
    float* out = (float*)d_out;

    bf16_t* za_bf = (bf16_t*)d_ws;                         // 4 MB
    bf16_t* zt_bf = za_bf + (size_t)BSZ * DDIM;            // 4 MB
    float*  s_row = (float*)(zt_bf + (size_t)BSZ * DDIM);  // 32 KB
    float*  s_col = s_row + BSZ;                           // 32 KB
    float*  total = s_col + BSZ;
    int*    flag  = (int*)(total + 1);
    int*    cnt   = flag + 1;

    cvt_kernel<<<dim3((BSZ * DDIM) / (256 * 8), 2), 256, 0, stream>>>(
        za, zt, za_bf, zt_bf, s_row);

    sim_mfma_kernel<<<dim3(64 * 64), 256, 0, stream>>>(
        za_bf, zt_bf, pid, s_row, s_col);

    finalize_rows<<<dim3(BSZ / 256), 256, 0, stream>>>(
        za, zt, pid, s_row, s_col, total, flag, cnt, out);
}

// Round 4
// 157.202 us; speedup vs baseline: 4.6906x; 1.0127x over previous
//
#include <hip/hip_runtime.h>
#include <math.h>

#define BSZ   8192
#define DDIM  256
#define SCALE 33.33333333333333f   // 1/0.03
#define C_OFF 34.0f                // fixed LSE offset: |sim*SCALE| <= 33.34

typedef __bf16 bf16_t;
typedef __bf16 bf16x8 __attribute__((ext_vector_type(8)));
typedef float  floatx4 __attribute__((ext_vector_type(4)));

// Stage one B chunk (128 cols x 32 k) from fp32 global -> bf16 LDS, swizzled.
// Physical chunk P (0..511) lives at LDS byte P*16; P = col*4 + slot_phys.
// Thread->P map (P = tid, tid+256) gives conflict-free ds_write_b128 banks.
// Logical k-slot = slot_phys ^ ((col>>1)&3)  (XOR swizzle, undone at read).
__device__ __forceinline__ void stage_B(const float* __restrict__ zt, int scol0,
                                        int t2, int kc, bf16_t* __restrict__ buf,
                                        int tid)
{
    #pragma unroll
    for (int h = 0; h < 2; h++) {
        const int P   = tid + h * 256;
        const int col = P >> 2;
        const int sp  = P & 3;
        const int sl  = sp ^ ((col >> 1) & 3);
        const float* g = zt + (size_t)(scol0 + t2 * 128 + col) * DDIM + kc * 32 + sl * 8;
        const float4 lo = *(const float4*)g;
        const float4 hi = *(const float4*)(g + 4);
        bf16x8 v;
        v[0] = (bf16_t)lo.x; v[1] = (bf16_t)lo.y; v[2] = (bf16_t)lo.z; v[3] = (bf16_t)lo.w;
        v[4] = (bf16_t)hi.x; v[5] = (bf16_t)hi.y; v[6] = (bf16_t)hi.z; v[7] = (bf16_t)hi.w;
        *(bf16x8*)((char*)buf + P * 16) = v;
    }
}

// ---------------------------------------------------------------- fused sim kernel
// Grid: 64 row-bands x 8 col-strips = 512 blocks, 256 threads (4 waves).
// Wave w owns rows [band*128 + 32w, +32); A fragments (full K=256) in VGPRs.
// Block sweeps 8 N-tiles of 128 cols; B chunks staged fp32->bf16->LDS,
// 4 rotating buffers, prefetch distance 2. Epilogue fuses mask+exp+row/col sums.
__global__ __launch_bounds__(256, 2) void sim_fused(
    const float* __restrict__ za, const float* __restrict__ zt,
    const int* __restrict__ pid,
    float* __restrict__ s_row, float* __restrict__ s_col,
    float* __restrict__ posv)
{
    __shared__ __align__(16) bf16_t Bs[4][128 * 32];   // 4 x 8 KB
    __shared__ int   pidr[128];
    __shared__ int   pidc[1024];
    __shared__ float colsum[1024];

    const int bid   = blockIdx.x;
    const int band  = bid >> 3;
    const int strip = bid & 7;          // strip pinned to XCD (bid%8 heuristic)
    const int row0  = band * 128;
    const int scol0 = strip * 1024;
    const int tid   = threadIdx.x;
    const int lane  = tid & 63, wid = tid >> 6;
    const int q     = lane >> 4, lc = lane & 15;
    const int rbase = row0 + wid * 32;
    const int xoff  = (lc >> 1) & 3;    // read-side XOR swizzle term

    if (tid < 128) pidr[tid] = pid[row0 + tid];
    #pragma unroll
    for (int h = 0; h < 4; h++) {
        pidc[tid + h * 256]   = pid[scol0 + tid + h * 256];
        colsum[tid + h * 256] = 0.f;
    }

    // A fragments: af[m][kc] -> A[row = rbase + m*16 + lc][k = kc*32 + q*8 + j]
    bf16x8 af[2][8];
    #pragma unroll
    for (int m = 0; m < 2; m++) {
        const float* ga = za + (size_t)(rbase + m * 16 + lc) * DDIM + q * 8;
        #pragma unroll
        for (int kc = 0; kc < 8; kc++) {
            const float4 lo = *(const float4*)(ga + kc * 32);
            const float4 hi = *(const float4*)(ga + kc * 32 + 4);
            bf16x8 v;
            v[0] = (bf16_t)lo.x; v[1] = (bf16_t)lo.y; v[2] = (bf16_t)lo.z; v[3] = (bf16_t)lo.w;
            v[4] = (bf16_t)hi.x; v[5] = (bf16_t)hi.y; v[6] = (bf16_t)hi.z; v[7] = (bf16_t)hi.w;
            af[m][kc] = v;
        }
    }

    // prologue: stage chunks s=0,1 into bufs 0,1
    stage_B(zt, scol0, 0, 0, Bs[0], tid);
    stage_B(zt, scol0, 0, 1, Bs[1], tid);

    floatx4 acc[2][8];
    #pragma unroll
    for (int m = 0; m < 2; m++)
        #pragma unroll
        for (int n = 0; n < 8; n++)
            acc[m][n] = (floatx4){0.f, 0.f, 0.f, 0.f};

    float rowp[8] = {0.f, 0.f, 0.f, 0.f, 0.f, 0.f, 0.f, 0.f};

    for (int t2 = 0; t2 < 8; t2++) {
        #pragma unroll
        for (int kc = 0; kc < 8; kc++) {
            __syncthreads();           // chunk (t2,kc) staged >= 2 iters ago

            // prefetch chunk s+2 into buf (kc+2)&3
            {
                int t2n = t2, kcn = kc + 2;
                if (kcn >= 8) { t2n = t2 + 1; kcn -= 8; }
                if (t2n < 8)
                    stage_B(zt, scol0, t2n, kcn, Bs[(kc + 2) & 3], tid);
            }

            const char* B = (const char*)Bs[kc & 3];
            bf16x8 bfr[8];
            #pragma unroll
            for (int n = 0; n < 8; n++)
                bfr[n] = *(const bf16x8*)(B + (n * 16 + lc) * 64 + ((q ^ xoff) * 16));

            #pragma unroll
            for (int m = 0; m < 2; m++)
                #pragma unroll
                for (int n = 0; n < 8; n++)
                    acc[m][n] = __builtin_amdgcn_mfma_f32_16x16x32_bf16(
                        af[m][kc], bfr[n], acc[m][n], 0, 0, 0);
        }

        // -------- epilogue for tile t2: mask + exp + row/col partials
        float colp[8];
        #pragma unroll
        for (int n = 0; n < 8; n++) colp[n] = 0.f;

        #pragma unroll
        for (int m = 0; m < 2; m++) {
            #pragma unroll
            for (int r = 0; r < 4; r++) {
                const int gr = rbase + m * 16 + q * 4 + r;
                const int pr = pidr[wid * 32 + m * 16 + q * 4 + r];
                float rsum = 0.f;
                #pragma unroll
                for (int n = 0; n < 8; n++) {
                    const int cl = t2 * 128 + n * 16 + lc;
                    const int gc = scol0 + cl;
                    const float logit = acc[m][n][r] * SCALE;
                    const bool diag = (gr == gc);
                    const bool keep = (pr != pidc[cl]) || diag;
                    const float e = keep ? __expf(logit - C_OFF) : 0.f;
                    rsum += e;
                    colp[n] += e;
                    if (diag) posv[gr] = logit;   // positive logit from MFMA diag
                }
                rowp[m * 4 + r] += rsum;
            }
        }

        // col partials: reduce across quads, quad 0 -> LDS accumulator
        #pragma unroll
        for (int n = 0; n < 8; n++) {
            colp[n] += __shfl_xor(colp[n], 16, 64);
            colp[n] += __shfl_xor(colp[n], 32, 64);
        }
        if (q == 0) {
            #pragma unroll
            for (int n = 0; n < 8; n++)
                atomicAdd(&colsum[t2 * 128 + n * 16 + lc], colp[n]);
        }

        // reset accumulators for next tile
        #pragma unroll
        for (int m = 0; m < 2; m++)
            #pragma unroll
            for (int n = 0; n < 8; n++)
                acc[m][n] = (floatx4){0.f, 0.f, 0.f, 0.f};
    }

    // -------- row sums: reduce over lc bits (cols), one atomic per row
    #pragma unroll
    for (int i = 0; i < 8; i++) {
        rowp[i] += __shfl_xor(rowp[i], 1, 64);
        rowp[i] += __shfl_xor(rowp[i], 2, 64);
        rowp[i] += __shfl_xor(rowp[i], 4, 64);
        rowp[i] += __shfl_xor(rowp[i], 8, 64);
    }
    float rw = rowp[0];
    #pragma unroll
    for (int idx = 1; idx < 8; idx++)
        rw = (lc == idx) ? rowp[idx] : rw;
    if (lc < 8)
        atomicAdd(&s_row[rbase + (lc >> 2) * 16 + q * 4 + (lc & 3)], rw);

    // -------- col sums: flush block accumulator to global
    __syncthreads();
    #pragma unroll
    for (int h = 0; h < 4; h++)
        atomicAdd(&s_col[scol0 + tid + h * 256], colsum[tid + h * 256]);
}

// ---------------------------------------------------------------- finalize (+ scalar write)
__global__ __launch_bounds__(256) void finalize_rows(
    const int* __restrict__ pid,
    const float* __restrict__ s_row, const float* __restrict__ s_col,
    const float* __restrict__ posv,
    float* __restrict__ total, int* __restrict__ flag, int* __restrict__ cnt,
    float* __restrict__ out)
{
    const int i = blockIdx.x * 256 + threadIdx.x;
    const float p = posv[i];
    const float c = (logf(s_row[i]) + C_OFF - p)
                  + (logf(s_col[i]) + C_OFF - p);

    float v = c;
    #pragma unroll
    for (int off = 32; off > 0; off >>= 1) v += __shfl_down(v, off, 64);
    if ((threadIdx.x & 63) == 0) atomicAdd(total, v);

    const unsigned long long m = __ballot(pid[i] != pid[0]);
    if (m != 0ull && (threadIdx.x & 63) == 0) atomicOr(flag, 1);

    __syncthreads();
    __threadfence();
    if (threadIdx.x == 0) {
        const int done = atomicAdd(cnt, 1);
        if (done == (int)gridDim.x - 1) {
            const float t = atomicAdd(total, 0.0f);
            const int   f = atomicOr(flag, 0);
            out[0] = f ? t / (2.0f * (float)BSZ) : 0.0f;
        }
    }
}

// ---------------------------------------------------------------- launcher
extern "C" void kernel_launch(void* const* d_in, const int* in_sizes, int n_in,
                              void* d_out, int out_size, void* d_ws, size_t ws_size,
                              hipStream_t stream)
{
    const float* za  = (const float*)d_in[0];
    const float* zt  = (const float*)d_in[1];
    const int*   pid = (const int*)d_in[2];
    float* out = (float*)d_out;

    // ws layout: s_row[8192] s_col[8192] total flag cnt | posv[8192]
    float* s_row = (float*)d_ws;
    float* s_col = s_row + BSZ;
    float* total = s_col + BSZ;
    int*   flag  = (int*)(total + 1);
    int*   cnt   = flag + 1;
    float* posv  = (float*)(cnt + 1);

    hipMemsetAsync(d_ws, 0, (size_t)(2 * BSZ + 3) * sizeof(float), stream);

    sim_fused<<<dim3(512), 256, 0, stream>>>(za, zt, pid, s_row, s_col, posv);

    finalize_rows<<<dim3(BSZ / 256), 256, 0, stream>>>(
        pid, s_row, s_col, posv, total, flag, cnt, out);
}